// Round 1
// baseline (997.866 us; speedup 1.0000x reference)
//
#include <hip/hip_runtime.h>
#include <math.h>

#define N_NODES_C 100000
#define N_EDGES_C 3200000

// ============================ CSR build ============================

__global__ void count_deg_kernel(const int* __restrict__ dst, int* __restrict__ deg1, int n_edges) {
    int e = blockIdx.x * blockDim.x + threadIdx.x;
    if (e < n_edges) atomicAdd(&deg1[dst[e] + 1], 1);
}

// inclusive scan of a[0..n) in chunks of 1024 (256 thr x 4), chunk totals -> bsums
__global__ __launch_bounds__(256) void scan_chunks_kernel(int* __restrict__ a, int n, int* __restrict__ bsums) {
    __shared__ int s[256];
    const int tid = threadIdx.x;
    int base = blockIdx.x * 1024 + tid * 4;
    int v[4];
#pragma unroll
    for (int i = 0; i < 4; ++i) v[i] = (base + i < n) ? a[base + i] : 0;
    int tsum = v[0] + v[1] + v[2] + v[3];
    s[tid] = tsum;
    __syncthreads();
    for (int off = 1; off < 256; off <<= 1) {
        int t = (tid >= off) ? s[tid - off] : 0;
        __syncthreads();
        s[tid] += t;
        __syncthreads();
    }
    int run = s[tid] - tsum;  // exclusive prefix for this thread
#pragma unroll
    for (int i = 0; i < 4; ++i) {
        run += v[i];
        if (base + i < n) a[base + i] = run;
    }
    if (tid == 255) bsums[blockIdx.x] = s[255];
}

// exclusive scan of bsums[0..nb), nb <= 128, single block of 128
__global__ __launch_bounds__(128) void scan_sums_kernel(int* __restrict__ bsums, int nb) {
    __shared__ int s[128];
    const int tid = threadIdx.x;
    int v = (tid < nb) ? bsums[tid] : 0;
    s[tid] = v;
    __syncthreads();
    for (int off = 1; off < 128; off <<= 1) {
        int t = (tid >= off) ? s[tid - off] : 0;
        __syncthreads();
        s[tid] += t;
        __syncthreads();
    }
    if (tid < nb) bsums[tid] = s[tid] - v;  // exclusive
}

__global__ __launch_bounds__(256) void scan_add_kernel(int* __restrict__ a, int n, const int* __restrict__ bsums) {
    int base = blockIdx.x * 1024 + threadIdx.x * 4;
    int add = bsums[blockIdx.x];
#pragma unroll
    for (int i = 0; i < 4; ++i)
        if (base + i < n) a[base + i] += add;
}

__global__ void cursor_init_kernel(const int* __restrict__ offs, int* __restrict__ cur, int n) {
    int i = blockIdx.x * blockDim.x + threadIdx.x;
    if (i < n) cur[i] = offs[i];
}

__global__ void fill_srcs_kernel(const int* __restrict__ src, const int* __restrict__ dst,
                                 int* __restrict__ cur, int* __restrict__ srcs, int n_edges) {
    int e = blockIdx.x * blockDim.x + threadIdx.x;
    if (e < n_edges) {
        int d = dst[e];
        int pos = atomicAdd(&cur[d], 1);
        srcs[pos] = src[e];
    }
}

// ============================ gather: out[n] = feat[n] + sum_{s in adj(n)} feat[s] ============================

template <int C>
__global__ __launch_bounds__(C) void gather_sum_kernel(const float* __restrict__ feat,
                                                       const int* __restrict__ offs,
                                                       const int* __restrict__ srcs,
                                                       float* __restrict__ out, int n_nodes) {
    const int n = blockIdx.x;
    const int ch = threadIdx.x;
    float acc = feat[(size_t)n * C + ch];
    const int s0 = offs[n], s1 = offs[n + 1];
    for (int i = s0; i < s1; ++i) {
        int s = srcs[i];
        acc += feat[(size_t)s * C + ch];
    }
    out[(size_t)n * C + ch] = acc;
}

// ============================ dense: out = relu(in @ W + b), OUT=64 ============================

template <int IN_DIM>
__global__ __launch_bounds__(256) void mlp_layer_kernel(const float* __restrict__ in,
                                                        const float* __restrict__ W,
                                                        const float* __restrict__ bias,
                                                        float* __restrict__ out, int n_nodes) {
    __shared__ float sW[IN_DIM * 64];
    __shared__ float sB[64];
    __shared__ float sIn[64][IN_DIM + 4];
    const int tid = threadIdx.x;
    for (int i = tid; i < IN_DIM * 16; i += 256) ((float4*)sW)[i] = ((const float4*)W)[i];
    if (tid < 64) sB[tid] = bias[tid];
    const int base = blockIdx.x * 64;
    for (int i = tid; i < 16 * IN_DIM; i += 256) {  // 64*IN_DIM/4 float4s
        int nl = i / (IN_DIM / 4);
        int k4 = i % (IN_DIM / 4);
        int n = base + nl;
        float4 v = make_float4(0.f, 0.f, 0.f, 0.f);
        if (n < n_nodes) v = ((const float4*)in)[(size_t)n * (IN_DIM / 4) + k4];
        *(float4*)&sIn[nl][k4 * 4] = v;
    }
    __syncthreads();
    const int tj = tid & 15, tn = tid >> 4;
    const int j0 = tj * 4, n0 = tn * 4;
    float acc[4][4];
#pragma unroll
    for (int i = 0; i < 4; ++i)
#pragma unroll
        for (int j = 0; j < 4; ++j) acc[i][j] = sB[j0 + j];
    for (int k = 0; k < IN_DIM; k += 4) {
        float4 a0 = *(const float4*)&sIn[n0 + 0][k];
        float4 a1 = *(const float4*)&sIn[n0 + 1][k];
        float4 a2 = *(const float4*)&sIn[n0 + 2][k];
        float4 a3 = *(const float4*)&sIn[n0 + 3][k];
        float4 w0 = *(const float4*)&sW[(k + 0) * 64 + j0];
        float4 w1 = *(const float4*)&sW[(k + 1) * 64 + j0];
        float4 w2 = *(const float4*)&sW[(k + 2) * 64 + j0];
        float4 w3 = *(const float4*)&sW[(k + 3) * 64 + j0];
#define GIN_STEP(ai, i)                                                                               \
        acc[i][0] += ai.x * w0.x; acc[i][1] += ai.x * w0.y; acc[i][2] += ai.x * w0.z; acc[i][3] += ai.x * w0.w; \
        acc[i][0] += ai.y * w1.x; acc[i][1] += ai.y * w1.y; acc[i][2] += ai.y * w1.z; acc[i][3] += ai.y * w1.w; \
        acc[i][0] += ai.z * w2.x; acc[i][1] += ai.z * w2.y; acc[i][2] += ai.z * w2.z; acc[i][3] += ai.z * w2.w; \
        acc[i][0] += ai.w * w3.x; acc[i][1] += ai.w * w3.y; acc[i][2] += ai.w * w3.z; acc[i][3] += ai.w * w3.w;
        GIN_STEP(a0, 0) GIN_STEP(a1, 1) GIN_STEP(a2, 2) GIN_STEP(a3, 3)
#undef GIN_STEP
    }
#pragma unroll
    for (int i = 0; i < 4; ++i) {
        int n = base + n0 + i;
        if (n < n_nodes) {
            float4 o;
            o.x = fmaxf(acc[i][0], 0.f);
            o.y = fmaxf(acc[i][1], 0.f);
            o.z = fmaxf(acc[i][2], 0.f);
            o.w = fmaxf(acc[i][3], 0.f);
            *(float4*)&out[(size_t)n * 64 + j0] = o;
        }
    }
}

// ============================ final: log_softmax(in @ Wf + bf), IN=64, OUT=40 ============================

__global__ __launch_bounds__(256) void final_logsoftmax_kernel(const float* __restrict__ in,
                                                               const float* __restrict__ W,
                                                               const float* __restrict__ bias,
                                                               float* __restrict__ out, int n_nodes) {
    __shared__ float sW[64 * 40];
    __shared__ float sB[40];
    __shared__ float sIn[100][68];
    __shared__ float sLog[100][40];
    const int tid = threadIdx.x;
    for (int i = tid; i < 64 * 10; i += 256) ((float4*)sW)[i] = ((const float4*)W)[i];
    if (tid < 40) sB[tid] = bias[tid];
    const int base = blockIdx.x * 100;
    for (int i = tid; i < 100 * 16; i += 256) {
        int nl = i / 16, k4 = i % 16;
        int n = base + nl;
        float4 v = make_float4(0.f, 0.f, 0.f, 0.f);
        if (n < n_nodes) v = ((const float4*)in)[(size_t)n * 16 + k4];
        *(float4*)&sIn[nl][k4 * 4] = v;
    }
    __syncthreads();
    if (tid < 250) {
        const int tj = tid % 10, tn = tid / 10;
        const int j0 = tj * 4, n0 = tn * 4;
        float acc[4][4];
#pragma unroll
        for (int i = 0; i < 4; ++i)
#pragma unroll
            for (int j = 0; j < 4; ++j) acc[i][j] = sB[j0 + j];
        for (int k = 0; k < 64; k += 4) {
            float4 a0 = *(const float4*)&sIn[n0 + 0][k];
            float4 a1 = *(const float4*)&sIn[n0 + 1][k];
            float4 a2 = *(const float4*)&sIn[n0 + 2][k];
            float4 a3 = *(const float4*)&sIn[n0 + 3][k];
            float4 w0 = *(const float4*)&sW[(k + 0) * 40 + j0];
            float4 w1 = *(const float4*)&sW[(k + 1) * 40 + j0];
            float4 w2 = *(const float4*)&sW[(k + 2) * 40 + j0];
            float4 w3 = *(const float4*)&sW[(k + 3) * 40 + j0];
#define GIN_STEP(ai, i)                                                                               \
            acc[i][0] += ai.x * w0.x; acc[i][1] += ai.x * w0.y; acc[i][2] += ai.x * w0.z; acc[i][3] += ai.x * w0.w; \
            acc[i][0] += ai.y * w1.x; acc[i][1] += ai.y * w1.y; acc[i][2] += ai.y * w1.z; acc[i][3] += ai.y * w1.w; \
            acc[i][0] += ai.z * w2.x; acc[i][1] += ai.z * w2.y; acc[i][2] += ai.z * w2.z; acc[i][3] += ai.z * w2.w; \
            acc[i][0] += ai.w * w3.x; acc[i][1] += ai.w * w3.y; acc[i][2] += ai.w * w3.z; acc[i][3] += ai.w * w3.w;
            GIN_STEP(a0, 0) GIN_STEP(a1, 1) GIN_STEP(a2, 2) GIN_STEP(a3, 3)
#undef GIN_STEP
        }
#pragma unroll
        for (int i = 0; i < 4; ++i)
            *(float4*)&sLog[n0 + i][j0] = make_float4(acc[i][0], acc[i][1], acc[i][2], acc[i][3]);
    }
    __syncthreads();
    for (int nl = tid; nl < 100; nl += 256) {
        int n = base + nl;
        if (n >= n_nodes) continue;
        float m = -1e30f;
        for (int j = 0; j < 40; ++j) m = fmaxf(m, sLog[nl][j]);
        float s = 0.f;
        for (int j = 0; j < 40; ++j) s += expf(sLog[nl][j] - m);
        float lse = m + logf(s);
        for (int j = 0; j < 40; j += 4) {
            float4 o;
            o.x = sLog[nl][j + 0] - lse;
            o.y = sLog[nl][j + 1] - lse;
            o.z = sLog[nl][j + 2] - lse;
            o.w = sLog[nl][j + 3] - lse;
            *(float4*)&out[(size_t)n * 40 + j] = o;
        }
    }
}

// ============================ launch ============================

extern "C" void kernel_launch(void* const* d_in, const int* in_sizes, int n_in,
                              void* d_out, int out_size, void* d_ws, size_t ws_size,
                              hipStream_t stream) {
    const float* x  = (const float*)d_in[0];
    const int*   ei = (const int*)d_in[1];   // [2, E] int32 per harness contract
    const float* W1 = (const float*)d_in[2];
    const float* b1 = (const float*)d_in[3];
    const float* W2 = (const float*)d_in[4];
    const float* b2 = (const float*)d_in[5];
    const float* W3 = (const float*)d_in[6];
    const float* b3 = (const float*)d_in[7];
    const float* W4 = (const float*)d_in[8];
    const float* b4 = (const float*)d_in[9];
    const float* Wf = (const float*)d_in[10];
    const float* bf = (const float*)d_in[11];
    float* outp = (float*)d_out;

    const int N = N_NODES_C, E = N_EDGES_C;
    const int* srcp = ei;
    const int* dstp = ei + E;

    // workspace layout (~116 MB total)
    char* ws = (char*)d_ws;
    int*   offs  = (int*)(ws);                         // (N+1) ints          [0, 400128)
    int*   cur   = (int*)(ws + 400128);                // N ints              [400128, 800256)
    int*   bsums = (int*)(ws + 800256);                // 128 ints            [800256, 800768)
    int*   srcs  = (int*)(ws + 800768);                // E ints              [800768, 13600768)
    float* F1    = (float*)(ws + 13600768);            // N*128 floats        [.., 64800768)
    float* F2    = (float*)(ws + 64800768);            // N*64 floats         [.., 90400768)
    float* F3    = (float*)(ws + 90400768);            // N*64 floats         [.., 116000768)

    // ---- CSR build ----
    hipMemsetAsync(offs, 0, (size_t)(N + 1) * sizeof(int), stream);
    count_deg_kernel<<<(E + 255) / 256, 256, 0, stream>>>(dstp, offs, E);
    const int n_scan = N + 1;
    const int nblk = (n_scan + 1023) / 1024;  // 98
    scan_chunks_kernel<<<nblk, 256, 0, stream>>>(offs, n_scan, bsums);
    scan_sums_kernel<<<1, 128, 0, stream>>>(bsums, nblk);
    scan_add_kernel<<<nblk, 256, 0, stream>>>(offs, n_scan, bsums);
    cursor_init_kernel<<<(N + 255) / 256, 256, 0, stream>>>(offs, cur, N);
    fill_srcs_kernel<<<(E + 255) / 256, 256, 0, stream>>>(srcp, dstp, cur, srcs, E);

    const int mlp_grid = (N + 63) / 64;  // 1563

    // ---- conv1: agg + MLP (relu inner, relu outer folded) ----
    gather_sum_kernel<128><<<N, 128, 0, stream>>>(x, offs, srcs, F1, N);
    mlp_layer_kernel<128><<<mlp_grid, 256, 0, stream>>>(F1, W1, b1, F2, N);
    mlp_layer_kernel<64><<<mlp_grid, 256, 0, stream>>>(F2, W2, b2, F3, N);

    // ---- conv2 ----
    gather_sum_kernel<64><<<N, 64, 0, stream>>>(F3, offs, srcs, F1, N);
    mlp_layer_kernel<64><<<mlp_grid, 256, 0, stream>>>(F1, W3, b3, F2, N);
    mlp_layer_kernel<64><<<mlp_grid, 256, 0, stream>>>(F2, W4, b4, F3, N);

    // ---- final fc + log_softmax ----
    final_logsoftmax_kernel<<<(N + 99) / 100, 256, 0, stream>>>(F3, Wf, bf, outp, N);
}

// Round 2
// 692.246 us; speedup vs baseline: 1.4415x; 1.4415x over previous
//
#include <hip/hip_runtime.h>
#include <math.h>

#define N_NODES_C 100000
#define N_EDGES_C 3200000

// ============================ CSR build ============================

__global__ void count_deg_kernel(const int* __restrict__ dst, int* __restrict__ deg1, int n_edges) {
    int e = blockIdx.x * blockDim.x + threadIdx.x;
    if (e < n_edges) atomicAdd(&deg1[dst[e] + 1], 1);
}

// inclusive scan of a[0..n) in chunks of 1024 (256 thr x 4), chunk totals -> bsums
__global__ __launch_bounds__(256) void scan_chunks_kernel(int* __restrict__ a, int n, int* __restrict__ bsums) {
    __shared__ int s[256];
    const int tid = threadIdx.x;
    int base = blockIdx.x * 1024 + tid * 4;
    int v[4];
#pragma unroll
    for (int i = 0; i < 4; ++i) v[i] = (base + i < n) ? a[base + i] : 0;
    int tsum = v[0] + v[1] + v[2] + v[3];
    s[tid] = tsum;
    __syncthreads();
    for (int off = 1; off < 256; off <<= 1) {
        int t = (tid >= off) ? s[tid - off] : 0;
        __syncthreads();
        s[tid] += t;
        __syncthreads();
    }
    int run = s[tid] - tsum;  // exclusive prefix for this thread
#pragma unroll
    for (int i = 0; i < 4; ++i) {
        run += v[i];
        if (base + i < n) a[base + i] = run;
    }
    if (tid == 255) bsums[blockIdx.x] = s[255];
}

// exclusive scan of bsums[0..nb), nb <= 128, single block of 128
__global__ __launch_bounds__(128) void scan_sums_kernel(int* __restrict__ bsums, int nb) {
    __shared__ int s[128];
    const int tid = threadIdx.x;
    int v = (tid < nb) ? bsums[tid] : 0;
    s[tid] = v;
    __syncthreads();
    for (int off = 1; off < 128; off <<= 1) {
        int t = (tid >= off) ? s[tid - off] : 0;
        __syncthreads();
        s[tid] += t;
        __syncthreads();
    }
    if (tid < nb) bsums[tid] = s[tid] - v;  // exclusive
}

__global__ __launch_bounds__(256) void scan_add_kernel(int* __restrict__ a, int n, const int* __restrict__ bsums) {
    int base = blockIdx.x * 1024 + threadIdx.x * 4;
    int add = bsums[blockIdx.x];
#pragma unroll
    for (int i = 0; i < 4; ++i)
        if (base + i < n) a[base + i] += add;
}

__global__ void fill_srcs_kernel(const int* __restrict__ src, const int* __restrict__ dst,
                                 const int* __restrict__ offs, int* __restrict__ cnt,
                                 int* __restrict__ srcs, int n_edges) {
    int e = blockIdx.x * blockDim.x + threadIdx.x;
    if (e < n_edges) {
        int d = dst[e];
        int pos = offs[d] + atomicAdd(&cnt[d], 1);
        srcs[pos] = src[e];
    }
}

// ============= gather64: out[n] = relu(feat[n] + sum_{s in adj(n)} feat[s] + bias) =============
// one wave (64 lanes = 64 channels) per node; neighbor loop unrolled x8 for MLP

__global__ __launch_bounds__(256) void gather64_kernel(const float* __restrict__ feat,
                                                       const int* __restrict__ offs,
                                                       const int* __restrict__ srcs,
                                                       const float* __restrict__ bias,
                                                       float* __restrict__ out, int n_nodes) {
    const int wave = threadIdx.x >> 6;
    const int lane = threadIdx.x & 63;
    const int n = blockIdx.x * 4 + wave;
    if (n >= n_nodes) return;
    float acc = feat[(size_t)n * 64 + lane];
    const int s0 = offs[n], s1 = offs[n + 1];
    int i = s0;
    for (; i + 8 <= s1; i += 8) {
        int sA[8];
#pragma unroll
        for (int u = 0; u < 8; ++u) sA[u] = srcs[i + u];
        float v[8];
#pragma unroll
        for (int u = 0; u < 8; ++u) v[u] = feat[(size_t)sA[u] * 64 + lane];
#pragma unroll
        for (int u = 0; u < 8; ++u) acc += v[u];
    }
    for (; i < s1; ++i) acc += feat[(size_t)srcs[i] * 64 + lane];
    acc = fmaxf(acc + bias[lane], 0.f);
    out[(size_t)n * 64 + lane] = acc;
}

// ============================ dense: out = [relu](in @ W [+ b]), OUT=64 ============================

template <int IN_DIM, bool RELU, bool HAS_BIAS>
__global__ __launch_bounds__(256) void mlp_layer_kernel(const float* __restrict__ in,
                                                        const float* __restrict__ W,
                                                        const float* __restrict__ bias,
                                                        float* __restrict__ out, int n_nodes) {
    __shared__ float sW[IN_DIM * 64];
    __shared__ float sB[64];
    __shared__ float sIn[64][IN_DIM + 4];
    const int tid = threadIdx.x;
    for (int i = tid; i < IN_DIM * 16; i += 256) ((float4*)sW)[i] = ((const float4*)W)[i];
    if (HAS_BIAS) {
        if (tid < 64) sB[tid] = bias[tid];
    }
    const int base = blockIdx.x * 64;
    for (int i = tid; i < 16 * IN_DIM; i += 256) {  // 64*IN_DIM/4 float4s
        int nl = i / (IN_DIM / 4);
        int k4 = i % (IN_DIM / 4);
        int n = base + nl;
        float4 v = make_float4(0.f, 0.f, 0.f, 0.f);
        if (n < n_nodes) v = ((const float4*)in)[(size_t)n * (IN_DIM / 4) + k4];
        *(float4*)&sIn[nl][k4 * 4] = v;
    }
    __syncthreads();
    const int tj = tid & 15, tn = tid >> 4;
    const int j0 = tj * 4, n0 = tn * 4;
    float acc[4][4];
#pragma unroll
    for (int i = 0; i < 4; ++i)
#pragma unroll
        for (int j = 0; j < 4; ++j) acc[i][j] = HAS_BIAS ? sB[j0 + j] : 0.f;
    for (int k = 0; k < IN_DIM; k += 4) {
        float4 a0 = *(const float4*)&sIn[n0 + 0][k];
        float4 a1 = *(const float4*)&sIn[n0 + 1][k];
        float4 a2 = *(const float4*)&sIn[n0 + 2][k];
        float4 a3 = *(const float4*)&sIn[n0 + 3][k];
        float4 w0 = *(const float4*)&sW[(k + 0) * 64 + j0];
        float4 w1 = *(const float4*)&sW[(k + 1) * 64 + j0];
        float4 w2 = *(const float4*)&sW[(k + 2) * 64 + j0];
        float4 w3 = *(const float4*)&sW[(k + 3) * 64 + j0];
#define GIN_STEP(ai, i)                                                                               \
        acc[i][0] += ai.x * w0.x; acc[i][1] += ai.x * w0.y; acc[i][2] += ai.x * w0.z; acc[i][3] += ai.x * w0.w; \
        acc[i][0] += ai.y * w1.x; acc[i][1] += ai.y * w1.y; acc[i][2] += ai.y * w1.z; acc[i][3] += ai.y * w1.w; \
        acc[i][0] += ai.z * w2.x; acc[i][1] += ai.z * w2.y; acc[i][2] += ai.z * w2.z; acc[i][3] += ai.z * w2.w; \
        acc[i][0] += ai.w * w3.x; acc[i][1] += ai.w * w3.y; acc[i][2] += ai.w * w3.z; acc[i][3] += ai.w * w3.w;
        GIN_STEP(a0, 0) GIN_STEP(a1, 1) GIN_STEP(a2, 2) GIN_STEP(a3, 3)
#undef GIN_STEP
    }
#pragma unroll
    for (int i = 0; i < 4; ++i) {
        int n = base + n0 + i;
        if (n < n_nodes) {
            float4 o;
            o.x = RELU ? fmaxf(acc[i][0], 0.f) : acc[i][0];
            o.y = RELU ? fmaxf(acc[i][1], 0.f) : acc[i][1];
            o.z = RELU ? fmaxf(acc[i][2], 0.f) : acc[i][2];
            o.w = RELU ? fmaxf(acc[i][3], 0.f) : acc[i][3];
            *(float4*)&out[(size_t)n * 64 + j0] = o;
        }
    }
}

// ============================ final: log_softmax(in @ Wf + bf), IN=64, OUT=40 ============================

__global__ __launch_bounds__(256) void final_logsoftmax_kernel(const float* __restrict__ in,
                                                               const float* __restrict__ W,
                                                               const float* __restrict__ bias,
                                                               float* __restrict__ out, int n_nodes) {
    __shared__ float sW[64 * 40];
    __shared__ float sB[40];
    __shared__ float sIn[100][68];
    __shared__ float sLog[100][40];
    const int tid = threadIdx.x;
    for (int i = tid; i < 64 * 10; i += 256) ((float4*)sW)[i] = ((const float4*)W)[i];
    if (tid < 40) sB[tid] = bias[tid];
    const int base = blockIdx.x * 100;
    for (int i = tid; i < 100 * 16; i += 256) {
        int nl = i / 16, k4 = i % 16;
        int n = base + nl;
        float4 v = make_float4(0.f, 0.f, 0.f, 0.f);
        if (n < n_nodes) v = ((const float4*)in)[(size_t)n * 16 + k4];
        *(float4*)&sIn[nl][k4 * 4] = v;
    }
    __syncthreads();
    if (tid < 250) {
        const int tj = tid % 10, tn = tid / 10;
        const int j0 = tj * 4, n0 = tn * 4;
        float acc[4][4];
#pragma unroll
        for (int i = 0; i < 4; ++i)
#pragma unroll
            for (int j = 0; j < 4; ++j) acc[i][j] = sB[j0 + j];
        for (int k = 0; k < 64; k += 4) {
            float4 a0 = *(const float4*)&sIn[n0 + 0][k];
            float4 a1 = *(const float4*)&sIn[n0 + 1][k];
            float4 a2 = *(const float4*)&sIn[n0 + 2][k];
            float4 a3 = *(const float4*)&sIn[n0 + 3][k];
            float4 w0 = *(const float4*)&sW[(k + 0) * 40 + j0];
            float4 w1 = *(const float4*)&sW[(k + 1) * 40 + j0];
            float4 w2 = *(const float4*)&sW[(k + 2) * 40 + j0];
            float4 w3 = *(const float4*)&sW[(k + 3) * 40 + j0];
#define GIN_STEP(ai, i)                                                                               \
            acc[i][0] += ai.x * w0.x; acc[i][1] += ai.x * w0.y; acc[i][2] += ai.x * w0.z; acc[i][3] += ai.x * w0.w; \
            acc[i][0] += ai.y * w1.x; acc[i][1] += ai.y * w1.y; acc[i][2] += ai.y * w1.z; acc[i][3] += ai.y * w1.w; \
            acc[i][0] += ai.z * w2.x; acc[i][1] += ai.z * w2.y; acc[i][2] += ai.z * w2.z; acc[i][3] += ai.z * w2.w; \
            acc[i][0] += ai.w * w3.x; acc[i][1] += ai.w * w3.y; acc[i][2] += ai.w * w3.z; acc[i][3] += ai.w * w3.w;
            GIN_STEP(a0, 0) GIN_STEP(a1, 1) GIN_STEP(a2, 2) GIN_STEP(a3, 3)
#undef GIN_STEP
        }
#pragma unroll
        for (int i = 0; i < 4; ++i)
            *(float4*)&sLog[n0 + i][j0] = make_float4(acc[i][0], acc[i][1], acc[i][2], acc[i][3]);
    }
    __syncthreads();
    for (int nl = tid; nl < 100; nl += 256) {
        int n = base + nl;
        if (n >= n_nodes) continue;
        float m = -1e30f;
        for (int j = 0; j < 40; ++j) m = fmaxf(m, sLog[nl][j]);
        float s = 0.f;
        for (int j = 0; j < 40; ++j) s += expf(sLog[nl][j] - m);
        float lse = m + logf(s);
        for (int j = 0; j < 40; j += 4) {
            float4 o;
            o.x = sLog[nl][j + 0] - lse;
            o.y = sLog[nl][j + 1] - lse;
            o.z = sLog[nl][j + 2] - lse;
            o.w = sLog[nl][j + 3] - lse;
            *(float4*)&out[(size_t)n * 40 + j] = o;
        }
    }
}

// ============================ launch ============================

extern "C" void kernel_launch(void* const* d_in, const int* in_sizes, int n_in,
                              void* d_out, int out_size, void* d_ws, size_t ws_size,
                              hipStream_t stream) {
    const float* x  = (const float*)d_in[0];
    const int*   ei = (const int*)d_in[1];   // [2, E] int32 per harness contract
    const float* W1 = (const float*)d_in[2];
    const float* b1 = (const float*)d_in[3];
    const float* W2 = (const float*)d_in[4];
    const float* b2 = (const float*)d_in[5];
    const float* W3 = (const float*)d_in[6];
    const float* b3 = (const float*)d_in[7];
    const float* W4 = (const float*)d_in[8];
    const float* b4 = (const float*)d_in[9];
    const float* Wf = (const float*)d_in[10];
    const float* bf = (const float*)d_in[11];
    float* outp = (float*)d_out;

    const int N = N_NODES_C, E = N_EDGES_C;
    const int* srcp = ei;
    const int* dstp = ei + E;

    // workspace layout
    char* ws = (char*)d_ws;
    int*   offs = (int*)(ws);                  // (N+1) ints   [0, 400004)
    int*   cnt  = (int*)(ws + 400128);         // N ints       [400128, 800128)
    int*   bsums= (int*)(ws + 800256);         // 128 ints
    int*   srcs = (int*)(ws + 800768);         // E ints       [.., 13600768)
    float* F1   = (float*)(ws + 13600768);     // N*64 floats  (25.6 MB)
    float* F2   = (float*)(ws + 39200768);     // N*64 floats
    float* F3   = (float*)(ws + 64800768);     // N*64 floats

    // ---- CSR build ----
    hipMemsetAsync(offs, 0, 800128, stream);   // offs + cnt in one memset
    count_deg_kernel<<<(E + 255) / 256, 256, 0, stream>>>(dstp, offs, E);
    const int n_scan = N + 1;
    const int nblk = (n_scan + 1023) / 1024;  // 98
    scan_chunks_kernel<<<nblk, 256, 0, stream>>>(offs, n_scan, bsums);
    scan_sums_kernel<<<1, 128, 0, stream>>>(bsums, nblk);
    scan_add_kernel<<<nblk, 256, 0, stream>>>(offs, n_scan, bsums);
    fill_srcs_kernel<<<(E + 255) / 256, 256, 0, stream>>>(srcp, dstp, offs, cnt, srcs, E);

    const int mlp_grid = (N + 63) / 64;      // 1563
    const int gat_grid = (N + 3) / 4;        // 25000

    // ---- conv1 via linearity: y = x@W1; h1 = relu(y + sum y[src] + b1); c1r = relu(h1@W2+b2) ----
    mlp_layer_kernel<128, false, false><<<mlp_grid, 256, 0, stream>>>(x, W1, nullptr, F1, N);
    gather64_kernel<<<gat_grid, 256, 0, stream>>>(F1, offs, srcs, b1, F2, N);
    mlp_layer_kernel<64, true, true><<<mlp_grid, 256, 0, stream>>>(F2, W2, b2, F3, N);

    // ---- conv2 via linearity: u = c1r@W3; h3 = relu(u + sum u[src] + b3); c2r = relu(h3@W4+b4) ----
    mlp_layer_kernel<64, false, false><<<mlp_grid, 256, 0, stream>>>(F3, W3, nullptr, F1, N);
    gather64_kernel<<<gat_grid, 256, 0, stream>>>(F1, offs, srcs, b3, F2, N);
    mlp_layer_kernel<64, true, true><<<mlp_grid, 256, 0, stream>>>(F2, W4, b4, F3, N);

    // ---- final fc + log_softmax ----
    final_logsoftmax_kernel<<<(N + 99) / 100, 256, 0, stream>>>(F3, Wf, bf, outp, N);
}